// Round 4
// baseline (232.091 us; speedup 1.0000x reference)
//
#include <hip/hip_runtime.h>
#include <hip/hip_fp16.h>
#include <math.h>

// OTAM cumulative soft-min DTW, wavefront-parallel, register-resident rows.
// dists: [200,200,32,32] f32 -> out[40000] f32 = cum[31][33].
//
// Mapping: lane l of each 32-lane half-wave owns DP row l; step t computes
// cell (l, m=t-l). Neighbor-row values arrive via DPP wave_shr:1.
// Softmin always 3-term (lambda=0.5), extra terms disabled by BIG (exp2->0):
//   v = mn + C2*log2( 2^{K(p1-mn)} + 2^{K(c-mn)} + 2^{K(x3-mn)} )
//   K = -2/ln2, C2 = -ln2/2.
// Row 0 (lane l==0) degenerates to cumsum via p1=x3=BIG (exact: log2(1)=0).
//
// LDS trick: tiles staged as fp16 with row l ROTATED left by l, so the
// element needed at step t sits at position (t-1)&31 for every lane. Each
// lane pre-loads its whole row (16 half2 = 4x ds_read_b128) into registers;
// the 64-step DP loop has ZERO LDS traffic and every extract is a
// compile-time-constant register select.

constexpr int QS = 40000;
constexpr int PPB = 8;  // problems per 256-thread block (2 per wave)

__device__ __forceinline__ float wave_shr1(float v) {
    // v_mov_b32 dpp wave_shr:1 — lane i gets lane i-1.
    // Lane 32 gets lane 31 (cross-half): harmless, l==0 never uses pm.
    int r = __builtin_amdgcn_update_dpp(0, __builtin_bit_cast(int, v),
                                        0x138 /*wave_shr:1*/, 0xF, 0xF, true);
    return __builtin_bit_cast(float, r);
}

__global__ __launch_bounds__(256, 8) void otam_wavefront(const float* __restrict__ dists,
                                                         float* __restrict__ out) {
    __shared__ __align__(16) __half lh[PPB * 1024];  // 8 x 32 rows x 32 halves = 16 KB
    const int tid = threadIdx.x;
    const int blockP0 = blockIdx.x * PPB;

    // ---- stage: coalesced float4 global loads -> fp16, rotated row writes ----
    {
        const float4* src = (const float4*)(dists + (size_t)blockP0 * 1024);
#pragma unroll
        for (int i = 0; i < 8; ++i) {
            int f = tid + 256 * i;     // float4 index in the block's 8K-float chunk
            float4 v = src[f];
            int flat = f << 2;         // flat float index
            int p = flat >> 10;        // problem 0..7
            int r = (flat >> 5) & 31;  // row
            int e0 = flat & 31;        // element base (multiple of 4)
            __half* row = &lh[(p << 10) + (r << 5)];
            int rb = (e0 + r) & 31;    // rotated position
            row[rb] = __float2half(v.x);
            row[(rb + 1) & 31] = __float2half(v.y);
            row[(rb + 2) & 31] = __float2half(v.z);
            row[(rb + 3) & 31] = __float2half(v.w);
        }
    }
    __syncthreads();

    const int lane = tid & 63;
    const int l = lane & 31;                      // my DP row
    const int pl = ((tid >> 6) << 1) + (lane >> 5);  // local problem index
    const bool l0 = (l == 0);

    // ---- whole rotated row into registers: 16 x half2 (4 x ds_read_b128) ----
    __half2 rh[16];
    {
        const __half2* rb2 = (const __half2*)&lh[(pl << 10) + (l << 5)];
#pragma unroll
        for (int k = 0; k < 16; ++k) rh[k] = rb2[k];
    }

    const float BIG = 1e30f;
    const float K = -2.8853900817779268f;    // -2/ln2
    const float C2 = -0.34657359027997264f;  // -ln2/2

    float myval = 0.f;  // v[l][m-1] (junk outside the active window — provably harmless)
    float pm1 = 0.f;    // prev_row[m-1]

#pragma unroll
    for (int t = 1; t <= 64; ++t) {
        float pm = wave_shr1(myval);            // prev_row[m] = lane l-1 after step t-1
        int j = (t - 1) & 31;                   // rotated extract position (lane-uniform!)
        __half2 hp = rh[j >> 1];
        float dval = (j & 1) ? __high2float(hp) : __low2float(hp);
        bool m1 = (l == t - 1);                 // m==1 (folds to false for t>32)
        bool m33 = (l == t - 33);               // m==33 (folds to false for t<34)
        float dm = m33 ? 0.f : dval;            // pad column at m==33
        float c = m1 ? 0.f : myval;             // col-0 value is 0 at problem start
        float p1 = m1 ? 0.f : pm1;              // prev_row[0] = 0
        p1 = l0 ? BIG : p1;                     // row 0: cumsum degeneration
        float x3 = ((m1 | m33) & (int)!l0) ? pm : BIG;  // diagonal/above extra term
        float mn = fminf(fminf(p1, c), x3);
        float nk = -K * mn;
        float e1 = __builtin_amdgcn_exp2f(fmaf(K, p1, nk));
        float e2 = __builtin_amdgcn_exp2f(fmaf(K, c, nk));
        float e3 = __builtin_amdgcn_exp2f(fmaf(K, x3, nk));
        float s = e1 + e2 + e3;
        myval = fmaf(C2, __builtin_amdgcn_logf(s), dm + mn);
        pm1 = pm;
    }

    if (l == 31) out[blockP0 + pl] = myval;
}

extern "C" void kernel_launch(void* const* d_in, const int* in_sizes, int n_in,
                              void* d_out, int out_size, void* d_ws, size_t ws_size,
                              hipStream_t stream) {
    const float* dists = (const float*)d_in[0];
    float* out = (float*)d_out;
    dim3 grid(QS / PPB);  // 5000 blocks
    dim3 block(256);
    hipLaunchKernelGGL(otam_wavefront, grid, block, 0, stream, dists, out);
}

// Round 5
// 227.044 us; speedup vs baseline: 1.0222x; 1.0222x over previous
//
#include <hip/hip_runtime.h>
#include <hip/hip_fp16.h>

// OTAM cumulative soft-min DTW, wavefront-parallel, register-resident rows.
// dists: [200,200,32,32] f32 -> out[40000] f32 = cum[31][33].
//
// Mapping: lane l of each 32-lane half-wave owns DP row l; step t computes
// cell (l, m=t-l). Neighbor-row values via DPP wave_shr:1.
// softmin2(a,b) = mn + C2*log2(1 + 2^{K*(mx-mn)})   (exact "1+" form: the
//   min term contributes exactly 1)  K=-2/ln2, C2=-ln2/2, lambda=0.5.
// m==1 cells (inputs 0,0,pm): softmin associativity + softmin2(0,0)=C2 gives
//   v = d + softmin2(C2, pm) — folded into the 2-term path.
// m==33 cells add a third term x3=pm (selected to BIG -> exp2 -> 0 elsewhere).
// Row 0 (l==0) degenerates to cumsum via a=BIG (exact: log2(1)=0).
//
// Event structure: m==1 only at t=l+1 (<=32), m==33 only at t=l+33 (>=33).
//   t=1        : peel — only (0,1) real: v = d[0][0] (pure extract)
//   t=2..32    : loop A — 2-term softmin, 1 exp + 1 log
//   t=33..64   : loop C — 3-term softmin, 2 exp + 1 log
//
// LDS trick (round 4): tiles staged fp16 with row l rotated left by l, so the
// element needed at step t sits at position (t-1)&31 for EVERY lane -> each
// lane preloads its row into 16 VGPRs; the DP loop has zero memory traffic.
//
// launch_bounds(256,4): 128 VGPRs — round 4's (256,8)=64 cap almost certainly
// spilled rh[16]+working set to scratch inside the loop.

constexpr int QS = 40000;
constexpr int PPB = 8;  // problems per 256-thread block (2 per wave)

__device__ __forceinline__ float wave_shr1(float v) {
    // v_mov_b32 dpp wave_shr:1 — lane i gets lane i-1.
    // Lane 32 gets lane 31 (cross-half): harmless, l==0 never consumes pm.
    int r = __builtin_amdgcn_update_dpp(0, __builtin_bit_cast(int, v),
                                        0x138 /*wave_shr:1*/, 0xF, 0xF, true);
    return __builtin_bit_cast(float, r);
}

__global__ __launch_bounds__(256, 4) void otam_wavefront(const float* __restrict__ dists,
                                                         float* __restrict__ out) {
    __shared__ __align__(16) __half lh[PPB * 1024];  // 8 x 32x32 halves = 16 KB
    const int tid = threadIdx.x;
    const int blockP0 = blockIdx.x * PPB;

    // ---- stage: coalesced float4 global loads -> fp16, rotated row writes ----
    {
        const float4* src = (const float4*)(dists + (size_t)blockP0 * 1024);
#pragma unroll
        for (int i = 0; i < 8; ++i) {
            int f = tid + 256 * i;
            float4 v = src[f];
            int flat = f << 2;
            int p = flat >> 10;
            int r = (flat >> 5) & 31;
            int e0 = flat & 31;
            __half* row = &lh[(p << 10) + (r << 5)];
            int rb = (e0 + r) & 31;
            row[rb] = __float2half(v.x);
            row[(rb + 1) & 31] = __float2half(v.y);
            row[(rb + 2) & 31] = __float2half(v.z);
            row[(rb + 3) & 31] = __float2half(v.w);
        }
    }
    __syncthreads();

    const int lane = tid & 63;
    const int l = lane & 31;
    const int pl = ((tid >> 6) << 1) + (lane >> 5);
    const bool l0 = (l == 0);

    // ---- whole rotated row into registers: 16 half2 (4x ds_read_b128) ----
    __half2 rh[16];
    {
        const __half2* rb2 = (const __half2*)&lh[(pl << 10) + (l << 5)];
#pragma unroll
        for (int k = 0; k < 16; ++k) rh[k] = rb2[k];
    }

    const float BIG = 1e30f;
    const float K = -2.8853900817779268f;    // -2/ln2
    const float C2 = -0.34657359027997264f;  // -ln2/2 == softmin2(0,0)

#define EXTRACT(t) \
    (((t - 1) & 1) ? __high2float(rh[((t - 1) & 31) >> 1]) : __low2float(rh[((t - 1) & 31) >> 1]))

    // t = 1 (peeled): only (l=0, m=1) is real: v = d[0][0]. Junk elsewhere is
    // provably never consumed (m==1 selects ignore myval/pm1).
    float myval = EXTRACT(1);
    float pm1 = 0.f;

    // ---- loop A: t = 2..32 — m1 events possible, no m33; 1 exp + 1 log ----
#pragma unroll
    for (int t = 2; t <= 32; ++t) {
        float pm = wave_shr1(myval);
        float dval = EXTRACT(t);
        bool m1 = (l == t - 1);
        float a = m1 ? C2 : pm1;   // softmin2(0,0) = C2 exactly
        a = l0 ? BIG : a;          // row-0 cumsum: kill the other term
        float b = m1 ? pm : myval; // column-0 carry resets at m==1
        float mn = fminf(a, b), mx = fmaxf(a, b);
        float e = __builtin_amdgcn_exp2f(K * (mx - mn));  // arg <= 0: safe
        myval = fmaf(C2, __builtin_amdgcn_logf(1.f + e), dval + mn);
        pm1 = pm;
    }

    // ---- loop C: t = 33..64 — m33 events, no m1; 2 exp + 1 log ----
#pragma unroll
    for (int t = 33; t <= 64; ++t) {
        float pm = wave_shr1(myval);
        float dval = EXTRACT(t);
        bool m33 = (l == t - 33);
        float dm = m33 ? 0.f : dval;        // pad column d == 0
        float a = l0 ? BIG : pm1;
        float b = myval;
        float x3 = (m33 && !l0) ? pm : BIG; // third (above) term, else identity
        float mn = fminf(a, b), mx = fmaxf(a, b);
        float nk = -K * mn;
        float e = __builtin_amdgcn_exp2f(fmaf(K, mx, nk));        // <= 1
        float a3 = fminf(fmaf(K, x3, nk), 100.f);                 // overflow guard
        float e3 = __builtin_amdgcn_exp2f(a3);
        float s = 1.f + e + e3;
        myval = fmaf(C2, __builtin_amdgcn_logf(s), dm + mn);
        pm1 = pm;
    }
#undef EXTRACT

    if (l == 31) out[blockP0 + pl] = myval;
}

extern "C" void kernel_launch(void* const* d_in, const int* in_sizes, int n_in,
                              void* d_out, int out_size, void* d_ws, size_t ws_size,
                              hipStream_t stream) {
    const float* dists = (const float*)d_in[0];
    float* out = (float*)d_out;
    dim3 grid(QS / PPB);  // 5000 blocks
    dim3 block(256);
    hipLaunchKernelGGL(otam_wavefront, grid, block, 0, stream, dists, out);
}